// Round 3
// baseline (436.565 us; speedup 1.0000x reference)
//
#include <hip/hip_runtime.h>
#include <math.h>

typedef unsigned long long u64;
typedef unsigned int u32;

#define B_ 8
#define N_ 1000
#define C_ 81
#define NC 80          // C-1 (background dropped)
#define K_ 100
#define M_ 28
#define IMG_W_ 1216.0f
#define IMG_H_ 800.0f
#define SCORE_TH 0.05f
#define NMS_TH 0.5f
#define BBOX_CLIP 4.135166556742356f  // log(1000/16)
#define CAP 80000      // worst-case survivors per image
#define NBUCKET 1152   // covers (score>0.05 .. 1.0] under (sb>>17) - 0x7A99
#define BUCKET_BASE 0x7A99

// workspace layout (bytes):
// [0, 2560)           pc_cnt   int[640]          (zeroed by memset)
// [2560, 2592)        counts   int[8]            (zeroed by memset)
// [2592, 5122592)     gkeys    u64[8*80000]
// [5122592, 10242592) pc_keys  u64[640*1000]

__device__ __forceinline__ void decode_box(const float* __restrict__ box_reg,
                                           const float* __restrict__ props,
                                           int row, int cls, float* o) {
    const float* pr = props + row * 4;
    float x1 = pr[0], y1 = pr[1], x2 = pr[2], y2 = pr[3];
    float w = x2 - x1, h = y2 - y1;
    float cx = x1 + 0.5f * w, cy = y1 + 0.5f * h;
    const float* r = box_reg + (size_t)row * (C_ * 4) + cls * 4;
    float dx = r[0] / 10.f, dy = r[1] / 10.f;
    float dw = fminf(r[2] / 5.f, BBOX_CLIP);
    float dh = fminf(r[3] / 5.f, BBOX_CLIP);
    float pcx = dx * w + cx, pcy = dy * h + cy;
    float pw = expf(dw) * w, ph = expf(dh) * h;
    o[0] = fminf(fmaxf(pcx - 0.5f * pw, 0.f), IMG_W_);
    o[1] = fminf(fmaxf(pcy - 0.5f * ph, 0.f), IMG_H_);
    o[2] = fminf(fmaxf(pcx + 0.5f * pw, 0.f), IMG_W_);
    o[3] = fminf(fmaxf(pcy + 0.5f * ph, 0.f), IMG_H_);
}

__device__ __forceinline__ void emit_det(int b, int k, u64 key,
                                         const float* __restrict__ box_reg,
                                         const float* __restrict__ props,
                                         float* __restrict__ out) {
    float* ob = out + (b * K_ + k) * 4;
    if (key == 0) {
        ob[0] = 0.f; ob[1] = 0.f; ob[2] = 0.f; ob[3] = 0.f;
        out[3200 + b * K_ + k] = 0.f;
        out[4000 + b * K_ + k] = 0.f;
        return;
    }
    u32 sb = (u32)(key >> 27);
    int flat = 0x1FFFF - (int)((key >> 10) & 0x1FFFF);
    int n = (int)(key & 1023);
    int c = flat / 1000;   // class-1
    float bx[4];
    decode_box(box_reg, props, b * N_ + n, c + 1, bx);
    ob[0] = bx[0]; ob[1] = bx[1]; ob[2] = bx[2]; ob[3] = bx[3];
    out[3200 + b * K_ + k] = __uint_as_float(sb);
    out[4000 + b * K_ + k] = (float)(c + 1);
}

// ------------- Kernel 1: wave-per-row softmax + threshold + per-class compaction -------------
__global__ __launch_bounds__(256) void k_score(const float* __restrict__ logits,
                                               int* __restrict__ pc_cnt,
                                               u64* __restrict__ pc_keys) {
    int row = blockIdx.x * 4 + (threadIdx.x >> 6);   // [0, 8000)
    int lane = threadIdx.x & 63;
    const float* lg = logits + row * C_;
    float v0 = lg[lane];
    float v1 = (lane < C_ - 64) ? lg[lane + 64] : -INFINITY;
    float m = fmaxf(v0, v1);
    #pragma unroll
    for (int o = 32; o; o >>= 1) m = fmaxf(m, __shfl_xor(m, o));
    float e0 = expf(v0 - m);
    float e1 = (lane < C_ - 64) ? expf(v1 - m) : 0.f;
    float s = e0 + e1;
    #pragma unroll
    for (int o = 32; o; o >>= 1) s += __shfl_xor(s, o);
    float inv = 1.f / s;
    int b = row / N_, n = row % N_;
    float s0 = e0 * inv;            // class = lane (lane>=1; lane 0 is background)
    if (lane >= 1 && s0 > SCORE_TH) {
        int idx = b * NC + (lane - 1);
        int p = atomicAdd(&pc_cnt[idx], 1);
        pc_keys[(size_t)idx * 1000 + p] =
            ((u64)__float_as_uint(s0) << 10) | (u32)(1023 - n);
    }
    float s1 = e1 * inv;            // class = lane + 64
    if (lane < C_ - 64 && s1 > SCORE_TH) {
        int idx = b * NC + (lane + 63);
        int p = atomicAdd(&pc_cnt[idx], 1);
        pc_keys[(size_t)idx * 1000 + p] =
            ((u64)__float_as_uint(s1) << 10) | (u32)(1023 - n);
    }
}

// ------------- Kernel 2: per-(b,class) single-wave sort + register NMS -------------
__global__ __launch_bounds__(64) void k_nms(const int* __restrict__ pc_cnt,
                                            const u64* __restrict__ pc_keys,
                                            const float* __restrict__ box_reg,
                                            const float* __restrict__ props,
                                            u64* __restrict__ gkeys,
                                            int* __restrict__ counts) {
    int bc = blockIdx.x;
    int b = bc / NC, c = bc % NC;   // class id = c+1
    int lane = threadIdx.x;
    int cnt = pc_cnt[bc];
    const u64* pk = pc_keys + (size_t)bc * 1000;

    __shared__ u64 skeys[1024];
    __shared__ float sbx[1024][4];
    __shared__ unsigned char skeep[1024];

    if (cnt <= 64) {
        // ---- fast path: registers only, zero barriers ----
        u64 key = (lane < cnt) ? pk[lane] : 0;
        #pragma unroll
        for (int k2 = 2; k2 <= 64; k2 <<= 1) {
            #pragma unroll
            for (int j = k2 >> 1; j; j >>= 1) {
                u64 p = __shfl_xor(key, j);
                bool takeMax = ((lane & j) == 0) == ((lane & k2) == 0);
                bool greater = key > p;
                key = (takeMax == greater) ? key : p;
            }
        }
        float x1 = 0.f, y1 = 0.f, x2 = 0.f, y2 = 0.f, area = 0.f;
        int n = 1023 - (int)(key & 1023);
        u32 sb = (u32)(key >> 10);
        if (lane < cnt) {
            float bx[4];
            decode_box(box_reg, props, b * N_ + n, c + 1, bx);
            x1 = bx[0]; y1 = bx[1]; x2 = bx[2]; y2 = bx[3];
            area = (x2 - x1) * (y2 - y1);
        }
        u64 keepm = (cnt >= 64) ? ~0ull : ((1ull << cnt) - 1ull);
        for (int i = 0; i < cnt; ++i) {
            if (!((keepm >> i) & 1ull)) continue;
            float ax1 = __shfl(x1, i), ay1 = __shfl(y1, i);
            float ax2 = __shfl(x2, i), ay2 = __shfl(y2, i);
            float aarea = __shfl(area, i);
            float lx = fmaxf(ax1, x1), ly = fmaxf(ay1, y1);
            float rx = fminf(ax2, x2), ry = fminf(ay2, y2);
            float iw = fmaxf(rx - lx, 0.f), ih = fmaxf(ry - ly, 0.f);
            float inter = iw * ih;
            float iou = inter / (aarea + area - inter + 1e-9f);
            bool sup = (lane > i) && (lane < cnt) && (iou > NMS_TH);
            keepm &= ~__ballot(sup);
        }
        int total = __popcll(keepm);
        int base = 0;
        if (lane == 0 && total) base = atomicAdd(&counts[b], total);
        base = __shfl(base, 0);
        if ((keepm >> lane) & 1ull) {
            int off = __popcll(keepm & ((1ull << lane) - 1ull));
            int flat = c * 1000 + lane;
            gkeys[(size_t)b * CAP + base + off] =
                ((u64)sb << 27) | ((u64)(0x1FFFF - flat) << 10) | (u32)n;
        }
    } else {
        // ---- cold path: LDS bitonic over 1024, sequential NMS ----
        for (int i = lane; i < 1024; i += 64) skeys[i] = (i < cnt) ? pk[i] : 0;
        __syncthreads();
        for (int k2 = 2; k2 <= 1024; k2 <<= 1) {
            for (int j = k2 >> 1; j; j >>= 1) {
                for (int i = lane; i < 1024; i += 64) {
                    int ixj = i ^ j;
                    if (ixj > i) {
                        u64 a = skeys[i], bb2 = skeys[ixj];
                        bool desc = ((i & k2) == 0);
                        if (desc ? (a < bb2) : (a > bb2)) { skeys[i] = bb2; skeys[ixj] = a; }
                    }
                }
                __syncthreads();
            }
        }
        for (int i = lane; i < cnt; i += 64) {
            u64 key = skeys[i];
            int n = 1023 - (int)(key & 1023);
            decode_box(box_reg, props, b * N_ + n, c + 1, sbx[i]);
            skeep[i] = 1;
        }
        __syncthreads();
        for (int i = 0; i < cnt; ++i) {
            if (skeep[i]) {
                float ax1 = sbx[i][0], ay1 = sbx[i][1], ax2 = sbx[i][2], ay2 = sbx[i][3];
                float a1 = (ax2 - ax1) * (ay2 - ay1);
                for (int j = i + 1 + lane; j < cnt; j += 64) {
                    float lx = fmaxf(ax1, sbx[j][0]), ly = fmaxf(ay1, sbx[j][1]);
                    float rx = fminf(ax2, sbx[j][2]), ry = fminf(ay2, sbx[j][3]);
                    float iw = fmaxf(rx - lx, 0.f), ih = fmaxf(ry - ly, 0.f);
                    float inter = iw * ih;
                    float a2 = (sbx[j][2] - sbx[j][0]) * (sbx[j][3] - sbx[j][1]);
                    float iou = inter / (a1 + a2 - inter + 1e-9f);
                    if (iou > NMS_TH) skeep[j] = 0;
                }
            }
            __syncthreads();
        }
        for (int i = lane; i < cnt; i += 64) {
            if (skeep[i]) {
                int p2 = atomicAdd(&counts[b], 1);
                u64 key = skeys[i];
                u32 sb = (u32)(key >> 10);
                int n = 1023 - (int)(key & 1023);
                int flat = c * 1000 + i;
                gkeys[(size_t)b * CAP + p2] =
                    ((u64)sb << 27) | ((u64)(0x1FFFF - flat) << 10) | (u32)n;
            }
        }
    }
}

// ------------- Kernel 3: per-image top-K via histogram select + small sort -------------
__global__ __launch_bounds__(256) void k_topk(const int* __restrict__ counts,
                                              u64* __restrict__ gkeys,
                                              const float* __restrict__ box_reg,
                                              const float* __restrict__ props,
                                              float* __restrict__ out) {
    int b = blockIdx.x;
    int tid = threadIdx.x;
    int cnt = counts[b];
    if (cnt > CAP) cnt = CAP;
    __shared__ u64 sk[4096];
    __shared__ u64 comp[1024];
    __shared__ int hist[NBUCKET];
    __shared__ int sT, sCompCnt;
    __shared__ u64 wk[4];
    __shared__ int wp[4];
    u64* gk = gkeys + (size_t)b * CAP;

    if (cnt <= 4096) {
        for (int i = tid; i < NBUCKET; i += 256) hist[i] = 0;
        if (tid == 0) sCompCnt = 0;
        for (int i = tid; i < cnt; i += 256) sk[i] = gk[i];
        __syncthreads();
        // histogram of the monotone 15-bit score prefix (key>>44)
        for (int i = tid; i < cnt; i += 256) {
            int bk = (int)(sk[i] >> 44) - BUCKET_BASE;
            bk = min(max(bk, 0), NBUCKET - 1);
            atomicAdd(&hist[bk], 1);
        }
        __syncthreads();
        // single-wave suffix scan from the top bucket: find threshold T
        if (tid < 64) {
            int lane = tid;
            int running = 0, T = 0;
            for (int step = 0; step < NBUCKET / 64; ++step) {
                int bucket = NBUCKET - 1 - (step * 64 + lane);
                int v = hist[bucket];
                #pragma unroll
                for (int o = 1; o < 64; o <<= 1) {
                    int t = __shfl_up(v, o);
                    if (lane >= o) v += t;
                }
                int cum = running + v;
                u64 mask = __ballot(cum >= K_);
                if (mask) {
                    int fl = __ffsll(mask) - 1;   // first (highest-bucket) crossing
                    T = NBUCKET - 1 - (step * 64 + fl);
                    break;
                }
                running = __shfl(cum, 63);
            }
            if (tid == 0) sT = T;
        }
        __syncthreads();
        int T = sT;
        // compact keys with bucket >= T (superset of top-K, typically ~100-300)
        for (int i = tid; i < cnt; i += 256) {
            u64 key = sk[i];
            int bk = (int)(key >> 44) - BUCKET_BASE;
            bk = min(max(bk, 0), NBUCKET - 1);
            if (bk >= T) {
                int p = atomicAdd(&sCompCnt, 1);
                if (p < 1024) comp[p] = key;
            }
        }
        __syncthreads();
        int cc = sCompCnt;
        if (cc <= 1024) {
            int SS = 128;                       // >= K_
            while (SS < cc) SS <<= 1;
            for (int i = cc + tid; i < SS; i += 256) comp[i] = 0;
            __syncthreads();
            for (int k2 = 2; k2 <= SS; k2 <<= 1) {
                for (int j = k2 >> 1; j; j >>= 1) {
                    for (int i = tid; i < SS; i += 256) {
                        int ixj = i ^ j;
                        if (ixj > i) {
                            u64 a = comp[i], bb2 = comp[ixj];
                            bool desc = ((i & k2) == 0);
                            if (desc ? (a < bb2) : (a > bb2)) { comp[i] = bb2; comp[ixj] = a; }
                        }
                    }
                    __syncthreads();
                }
            }
            if (tid < K_) emit_det(b, tid, (tid < SS) ? comp[tid] : 0, box_reg, props, out);
        } else {
            // improbable fallback: full bitonic over sk[4096]
            for (int i = cnt + tid; i < 4096; i += 256) sk[i] = 0;
            __syncthreads();
            for (int k2 = 2; k2 <= 4096; k2 <<= 1) {
                for (int j = k2 >> 1; j; j >>= 1) {
                    for (int i = tid; i < 4096; i += 256) {
                        int ixj = i ^ j;
                        if (ixj > i) {
                            u64 a = sk[i], bb2 = sk[ixj];
                            bool desc = ((i & k2) == 0);
                            if (desc ? (a < bb2) : (a > bb2)) { sk[i] = bb2; sk[ixj] = a; }
                        }
                    }
                    __syncthreads();
                }
            }
            if (tid < K_) emit_det(b, tid, sk[tid], box_reg, props, out);
        }
    } else {
        // cold fallback: iterative argmax over global list
        for (int k = 0; k < K_; ++k) {
            u64 best = 0; int bpos = 0;
            for (int i = tid; i < cnt; i += 256) {
                u64 v = gk[i];
                if (v > best) { best = v; bpos = i; }
            }
            for (int o = 32; o; o >>= 1) {
                u64 ov = __shfl_down(best, o);
                int op = __shfl_down(bpos, o);
                if (ov > best) { best = ov; bpos = op; }
            }
            if ((tid & 63) == 0) { wk[tid >> 6] = best; wp[tid >> 6] = bpos; }
            __syncthreads();
            if (tid == 0) {
                for (int w2 = 1; w2 < 4; ++w2)
                    if (wk[w2] > best) { best = wk[w2]; bpos = wp[w2]; }
                emit_det(b, k, best, box_reg, props, out);
                if (best) gk[bpos] = 0;
            }
            __threadfence();
            __syncthreads();
        }
    }
}

// ------------- Kernel 4: mask sigmoid gather (float4) -------------
__global__ __launch_bounds__(256) void k_mask(const float* __restrict__ mask_logits,
                                              float* __restrict__ out) {
    int idx = blockIdx.x * 256 + threadIdx.x;      // over B*K*196 float4s
    if (idx >= B_ * K_ * 196) return;
    int p = idx % 196;
    int bk = idx / 196;                            // b*K + k
    int label = (int)out[4000 + bk];               // exact small-int float
    const float4* src = (const float4*)mask_logits;
    float4 v = src[((size_t)bk * C_ + label) * 196 + p];
    float4 r;
    r.x = 1.f / (1.f + expf(-v.x));
    r.y = 1.f / (1.f + expf(-v.y));
    r.z = 1.f / (1.f + expf(-v.z));
    r.w = 1.f / (1.f + expf(-v.w));
    ((float4*)(out + 4800))[idx] = r;
}

extern "C" void kernel_launch(void* const* d_in, const int* in_sizes, int n_in,
                              void* d_out, int out_size, void* d_ws, size_t ws_size,
                              hipStream_t stream) {
    const float* logits   = (const float*)d_in[0];  // [B*N, C]
    const float* box_reg  = (const float*)d_in[1];  // [B*N, C*4]
    const float* props    = (const float*)d_in[2];  // [B, N, 4]
    const float* mask_log = (const float*)d_in[3];  // [B, K, C, M, M]
    float* out = (float*)d_out;

    char* ws = (char*)d_ws;
    int* pc_cnt  = (int*)ws;                  // 640 ints
    int* counts  = (int*)(ws + 2560);         // 8 ints
    u64* gkeys   = (u64*)(ws + 2592);         // 8*80000 u64
    u64* pc_keys = (u64*)(ws + 5122592);      // 640*1000 u64

    hipMemsetAsync(ws, 0, 2592, stream);
    k_score<<<2000, 256, 0, stream>>>(logits, pc_cnt, pc_keys);
    k_nms<<<B_ * NC, 64, 0, stream>>>(pc_cnt, pc_keys, box_reg, props, gkeys, counts);
    k_topk<<<B_, 256, 0, stream>>>(counts, gkeys, box_reg, props, out);
    k_mask<<<(B_ * K_ * 196 + 255) / 256, 256, 0, stream>>>(mask_log, out);
}

// Round 4
// 281.075 us; speedup vs baseline: 1.5532x; 1.5532x over previous
//
#include <hip/hip_runtime.h>
#include <math.h>

typedef unsigned long long u64;
typedef unsigned int u32;

#define B_ 8
#define N_ 1000
#define C_ 81
#define NC 80          // C-1 (background dropped)
#define K_ 100
#define M_ 28
#define IMG_W_ 1216.0f
#define IMG_H_ 800.0f
#define SCORE_TH 0.05f
#define NMS_TH 0.5f
#define BBOX_CLIP 4.135166556742356f  // log(1000/16)
#define CAP 80000      // worst-case survivors per image
// bucket = key>>44 = score_bits>>17 (top 15 bits: sign+exp+6 mantissa).
// score in (0.05, 1.0]: 0x3D4CCCCD>>17 = 0x1EA6 .. 0x3F800000>>17 = 0x1FC0 -> 283 buckets.
#define BUCKET_BASE 0x1EA6
#define NBUCKET 320

// workspace layout (bytes):
// [0, 2560)           pc_cnt   int[640]          (zeroed by memset)
// [2560, 2592)        counts   int[8]            (zeroed by memset)
// [2592, 5122592)     gkeys    u64[8*80000]
// [5122592, 10242592) pc_keys  u64[640*1000]

__device__ __forceinline__ void decode_box(const float* __restrict__ box_reg,
                                           const float* __restrict__ props,
                                           int row, int cls, float* o) {
    const float* pr = props + row * 4;
    float x1 = pr[0], y1 = pr[1], x2 = pr[2], y2 = pr[3];
    float w = x2 - x1, h = y2 - y1;
    float cx = x1 + 0.5f * w, cy = y1 + 0.5f * h;
    const float* r = box_reg + (size_t)row * (C_ * 4) + cls * 4;
    float dx = r[0] / 10.f, dy = r[1] / 10.f;
    float dw = fminf(r[2] / 5.f, BBOX_CLIP);
    float dh = fminf(r[3] / 5.f, BBOX_CLIP);
    float pcx = dx * w + cx, pcy = dy * h + cy;
    float pw = expf(dw) * w, ph = expf(dh) * h;
    o[0] = fminf(fmaxf(pcx - 0.5f * pw, 0.f), IMG_W_);
    o[1] = fminf(fmaxf(pcy - 0.5f * ph, 0.f), IMG_H_);
    o[2] = fminf(fmaxf(pcx + 0.5f * pw, 0.f), IMG_W_);
    o[3] = fminf(fmaxf(pcy + 0.5f * ph, 0.f), IMG_H_);
}

__device__ __forceinline__ void emit_det(int b, int k, u64 key,
                                         const float* __restrict__ box_reg,
                                         const float* __restrict__ props,
                                         float* __restrict__ out) {
    float* ob = out + (b * K_ + k) * 4;
    if (key == 0) {
        ob[0] = 0.f; ob[1] = 0.f; ob[2] = 0.f; ob[3] = 0.f;
        out[3200 + b * K_ + k] = 0.f;
        out[4000 + b * K_ + k] = 0.f;
        return;
    }
    u32 sb = (u32)(key >> 27);
    int flat = 0x1FFFF - (int)((key >> 10) & 0x1FFFF);
    int n = (int)(key & 1023);
    int c = flat / 1000;   // class-1
    float bx[4];
    decode_box(box_reg, props, b * N_ + n, c + 1, bx);
    ob[0] = bx[0]; ob[1] = bx[1]; ob[2] = bx[2]; ob[3] = bx[3];
    out[3200 + b * K_ + k] = __uint_as_float(sb);
    out[4000 + b * K_ + k] = (float)(c + 1);
}

// ------------- Kernel 1: wave-per-row softmax + threshold + per-class compaction -------------
__global__ __launch_bounds__(256) void k_score(const float* __restrict__ logits,
                                               int* __restrict__ pc_cnt,
                                               u64* __restrict__ pc_keys) {
    int row = blockIdx.x * 4 + (threadIdx.x >> 6);   // [0, 8000)
    int lane = threadIdx.x & 63;
    const float* lg = logits + row * C_;
    float v0 = lg[lane];
    float v1 = (lane < C_ - 64) ? lg[lane + 64] : -INFINITY;
    float m = fmaxf(v0, v1);
    #pragma unroll
    for (int o = 32; o; o >>= 1) m = fmaxf(m, __shfl_xor(m, o));
    float e0 = expf(v0 - m);
    float e1 = (lane < C_ - 64) ? expf(v1 - m) : 0.f;
    float s = e0 + e1;
    #pragma unroll
    for (int o = 32; o; o >>= 1) s += __shfl_xor(s, o);
    float inv = 1.f / s;
    int b = row / N_, n = row % N_;
    float s0 = e0 * inv;            // class = lane (lane>=1; lane 0 is background)
    if (lane >= 1 && s0 > SCORE_TH) {
        int idx = b * NC + (lane - 1);
        int p = atomicAdd(&pc_cnt[idx], 1);
        pc_keys[(size_t)idx * 1000 + p] =
            ((u64)__float_as_uint(s0) << 10) | (u32)(1023 - n);
    }
    float s1 = e1 * inv;            // class = lane + 64
    if (lane < C_ - 64 && s1 > SCORE_TH) {
        int idx = b * NC + (lane + 63);
        int p = atomicAdd(&pc_cnt[idx], 1);
        pc_keys[(size_t)idx * 1000 + p] =
            ((u64)__float_as_uint(s1) << 10) | (u32)(1023 - n);
    }
}

// ------------- Kernel 2: per-(b,class) single-wave sort + register NMS -------------
__global__ __launch_bounds__(64) void k_nms(const int* __restrict__ pc_cnt,
                                            const u64* __restrict__ pc_keys,
                                            const float* __restrict__ box_reg,
                                            const float* __restrict__ props,
                                            u64* __restrict__ gkeys,
                                            int* __restrict__ counts) {
    int bc = blockIdx.x;
    int b = bc / NC, c = bc % NC;   // class id = c+1
    int lane = threadIdx.x;
    int cnt = pc_cnt[bc];
    const u64* pk = pc_keys + (size_t)bc * 1000;

    __shared__ u64 skeys[1024];
    __shared__ float sbx[1024][4];
    __shared__ unsigned char skeep[1024];

    if (cnt <= 64) {
        // ---- fast path: registers only, zero barriers ----
        u64 key = (lane < cnt) ? pk[lane] : 0;
        #pragma unroll
        for (int k2 = 2; k2 <= 64; k2 <<= 1) {
            #pragma unroll
            for (int j = k2 >> 1; j; j >>= 1) {
                u64 p = __shfl_xor(key, j);
                bool takeMax = ((lane & j) == 0) == ((lane & k2) == 0);
                bool greater = key > p;
                key = (takeMax == greater) ? key : p;
            }
        }
        float x1 = 0.f, y1 = 0.f, x2 = 0.f, y2 = 0.f, area = 0.f;
        int n = 1023 - (int)(key & 1023);
        u32 sb = (u32)(key >> 10);
        if (lane < cnt) {
            float bx[4];
            decode_box(box_reg, props, b * N_ + n, c + 1, bx);
            x1 = bx[0]; y1 = bx[1]; x2 = bx[2]; y2 = bx[3];
            area = (x2 - x1) * (y2 - y1);
        }
        u64 keepm = (cnt >= 64) ? ~0ull : ((1ull << cnt) - 1ull);
        for (int i = 0; i < cnt; ++i) {
            if (!((keepm >> i) & 1ull)) continue;
            float ax1 = __shfl(x1, i), ay1 = __shfl(y1, i);
            float ax2 = __shfl(x2, i), ay2 = __shfl(y2, i);
            float aarea = __shfl(area, i);
            float lx = fmaxf(ax1, x1), ly = fmaxf(ay1, y1);
            float rx = fminf(ax2, x2), ry = fminf(ay2, y2);
            float iw = fmaxf(rx - lx, 0.f), ih = fmaxf(ry - ly, 0.f);
            float inter = iw * ih;
            float iou = inter / (aarea + area - inter + 1e-9f);
            bool sup = (lane > i) && (lane < cnt) && (iou > NMS_TH);
            keepm &= ~__ballot(sup);
        }
        int total = __popcll(keepm);
        int base = 0;
        if (lane == 0 && total) base = atomicAdd(&counts[b], total);
        base = __shfl(base, 0);
        if ((keepm >> lane) & 1ull) {
            int off = __popcll(keepm & ((1ull << lane) - 1ull));
            int flat = c * 1000 + lane;
            gkeys[(size_t)b * CAP + base + off] =
                ((u64)sb << 27) | ((u64)(0x1FFFF - flat) << 10) | (u32)n;
        }
    } else {
        // ---- cold path: LDS bitonic over 1024, sequential NMS ----
        for (int i = lane; i < 1024; i += 64) skeys[i] = (i < cnt) ? pk[i] : 0;
        __syncthreads();
        for (int k2 = 2; k2 <= 1024; k2 <<= 1) {
            for (int j = k2 >> 1; j; j >>= 1) {
                for (int i = lane; i < 1024; i += 64) {
                    int ixj = i ^ j;
                    if (ixj > i) {
                        u64 a = skeys[i], bb2 = skeys[ixj];
                        bool desc = ((i & k2) == 0);
                        if (desc ? (a < bb2) : (a > bb2)) { skeys[i] = bb2; skeys[ixj] = a; }
                    }
                }
                __syncthreads();
            }
        }
        for (int i = lane; i < cnt; i += 64) {
            u64 key = skeys[i];
            int n = 1023 - (int)(key & 1023);
            decode_box(box_reg, props, b * N_ + n, c + 1, sbx[i]);
            skeep[i] = 1;
        }
        __syncthreads();
        for (int i = 0; i < cnt; ++i) {
            if (skeep[i]) {
                float ax1 = sbx[i][0], ay1 = sbx[i][1], ax2 = sbx[i][2], ay2 = sbx[i][3];
                float a1 = (ax2 - ax1) * (ay2 - ay1);
                for (int j = i + 1 + lane; j < cnt; j += 64) {
                    float lx = fmaxf(ax1, sbx[j][0]), ly = fmaxf(ay1, sbx[j][1]);
                    float rx = fminf(ax2, sbx[j][2]), ry = fminf(ay2, sbx[j][3]);
                    float iw = fmaxf(rx - lx, 0.f), ih = fmaxf(ry - ly, 0.f);
                    float inter = iw * ih;
                    float a2 = (sbx[j][2] - sbx[j][0]) * (sbx[j][3] - sbx[j][1]);
                    float iou = inter / (a1 + a2 - inter + 1e-9f);
                    if (iou > NMS_TH) skeep[j] = 0;
                }
            }
            __syncthreads();
        }
        for (int i = lane; i < cnt; i += 64) {
            if (skeep[i]) {
                int p2 = atomicAdd(&counts[b], 1);
                u64 key = skeys[i];
                u32 sb = (u32)(key >> 10);
                int n = 1023 - (int)(key & 1023);
                int flat = c * 1000 + i;
                gkeys[(size_t)b * CAP + p2] =
                    ((u64)sb << 27) | ((u64)(0x1FFFF - flat) << 10) | (u32)n;
            }
        }
    }
}

// ------------- Kernel 3: per-image top-K via histogram select + small sort -------------
__global__ __launch_bounds__(256) void k_topk(const int* __restrict__ counts,
                                              u64* __restrict__ gkeys,
                                              const float* __restrict__ box_reg,
                                              const float* __restrict__ props,
                                              float* __restrict__ out) {
    int b = blockIdx.x;
    int tid = threadIdx.x;
    int cnt = counts[b];
    if (cnt > CAP) cnt = CAP;
    __shared__ u64 sk[4096];
    __shared__ u64 comp[2048];
    __shared__ int hist[NBUCKET];
    __shared__ int sT, sCompCnt;
    __shared__ u64 wk[4];
    __shared__ int wp[4];
    u64* gk = gkeys + (size_t)b * CAP;

    if (cnt <= 4096) {
        for (int i = tid; i < NBUCKET; i += 256) hist[i] = 0;
        if (tid == 0) sCompCnt = 0;
        for (int i = tid; i < cnt; i += 256) sk[i] = gk[i];
        __syncthreads();
        // histogram of the monotone 15-bit score prefix (key>>44)
        for (int i = tid; i < cnt; i += 256) {
            int bk = (int)(sk[i] >> 44) - BUCKET_BASE;
            bk = min(max(bk, 0), NBUCKET - 1);
            atomicAdd(&hist[bk], 1);
        }
        __syncthreads();
        // single-wave suffix scan from top bucket: smallest T with count(bucket>=T) >= K
        if (tid < 64) {
            int lane = tid;
            int running = 0, T = 0;
            for (int step = 0; step < NBUCKET / 64; ++step) {
                int bucket = NBUCKET - 1 - (step * 64 + lane);
                int v = hist[bucket];
                #pragma unroll
                for (int o = 1; o < 64; o <<= 1) {
                    int t = __shfl_up(v, o);
                    if (lane >= o) v += t;
                }
                int cum = running + v;
                u64 mask = __ballot(cum >= K_);
                if (mask) {
                    int fl = __ffsll(mask) - 1;   // first (highest-bucket) crossing
                    T = NBUCKET - 1 - (step * 64 + fl);
                    break;
                }
                running = __shfl(cum, 63);
            }
            if (tid == 0) sT = T;
        }
        __syncthreads();
        int T = sT;
        // compact keys with bucket >= T (superset of top-K, typically ~100-300)
        for (int i = tid; i < cnt; i += 256) {
            u64 key = sk[i];
            int bk = (int)(key >> 44) - BUCKET_BASE;
            bk = min(max(bk, 0), NBUCKET - 1);
            if (bk >= T) {
                int p = atomicAdd(&sCompCnt, 1);
                if (p < 2048) comp[p] = key;
            }
        }
        __syncthreads();
        int cc = sCompCnt;
        if (cc <= 2048) {
            int SS = 128;                       // >= K_
            while (SS < cc) SS <<= 1;
            for (int i = cc + tid; i < SS; i += 256) comp[i] = 0;
            __syncthreads();
            for (int k2 = 2; k2 <= SS; k2 <<= 1) {
                for (int j = k2 >> 1; j; j >>= 1) {
                    for (int i = tid; i < SS; i += 256) {
                        int ixj = i ^ j;
                        if (ixj > i) {
                            u64 a = comp[i], bb2 = comp[ixj];
                            bool desc = ((i & k2) == 0);
                            if (desc ? (a < bb2) : (a > bb2)) { comp[i] = bb2; comp[ixj] = a; }
                        }
                    }
                    __syncthreads();
                }
            }
            if (tid < K_) emit_det(b, tid, (tid < SS) ? comp[tid] : 0, box_reg, props, out);
        } else {
            // improbable fallback: full bitonic over sk[4096]
            for (int i = cnt + tid; i < 4096; i += 256) sk[i] = 0;
            __syncthreads();
            for (int k2 = 2; k2 <= 4096; k2 <<= 1) {
                for (int j = k2 >> 1; j; j >>= 1) {
                    for (int i = tid; i < 4096; i += 256) {
                        int ixj = i ^ j;
                        if (ixj > i) {
                            u64 a = sk[i], bb2 = sk[ixj];
                            bool desc = ((i & k2) == 0);
                            if (desc ? (a < bb2) : (a > bb2)) { sk[i] = bb2; sk[ixj] = a; }
                        }
                    }
                    __syncthreads();
                }
            }
            if (tid < K_) emit_det(b, tid, sk[tid], box_reg, props, out);
        }
    } else {
        // cold fallback: iterative argmax over global list
        for (int k = 0; k < K_; ++k) {
            u64 best = 0; int bpos = 0;
            for (int i = tid; i < cnt; i += 256) {
                u64 v = gk[i];
                if (v > best) { best = v; bpos = i; }
            }
            for (int o = 32; o; o >>= 1) {
                u64 ov = __shfl_down(best, o);
                int op = __shfl_down(bpos, o);
                if (ov > best) { best = ov; bpos = op; }
            }
            if ((tid & 63) == 0) { wk[tid >> 6] = best; wp[tid >> 6] = bpos; }
            __syncthreads();
            if (tid == 0) {
                for (int w2 = 1; w2 < 4; ++w2)
                    if (wk[w2] > best) { best = wk[w2]; bpos = wp[w2]; }
                emit_det(b, k, best, box_reg, props, out);
                if (best) gk[bpos] = 0;
            }
            __threadfence();
            __syncthreads();
        }
    }
}

// ------------- Kernel 4: mask sigmoid gather (float4) -------------
__global__ __launch_bounds__(256) void k_mask(const float* __restrict__ mask_logits,
                                              float* __restrict__ out) {
    int idx = blockIdx.x * 256 + threadIdx.x;      // over B*K*196 float4s
    if (idx >= B_ * K_ * 196) return;
    int p = idx % 196;
    int bk = idx / 196;                            // b*K + k
    int label = (int)out[4000 + bk];               // exact small-int float
    const float4* src = (const float4*)mask_logits;
    float4 v = src[((size_t)bk * C_ + label) * 196 + p];
    float4 r;
    r.x = 1.f / (1.f + expf(-v.x));
    r.y = 1.f / (1.f + expf(-v.y));
    r.z = 1.f / (1.f + expf(-v.z));
    r.w = 1.f / (1.f + expf(-v.w));
    ((float4*)(out + 4800))[idx] = r;
}

extern "C" void kernel_launch(void* const* d_in, const int* in_sizes, int n_in,
                              void* d_out, int out_size, void* d_ws, size_t ws_size,
                              hipStream_t stream) {
    const float* logits   = (const float*)d_in[0];  // [B*N, C]
    const float* box_reg  = (const float*)d_in[1];  // [B*N, C*4]
    const float* props    = (const float*)d_in[2];  // [B, N, 4]
    const float* mask_log = (const float*)d_in[3];  // [B, K, C, M, M]
    float* out = (float*)d_out;

    char* ws = (char*)d_ws;
    int* pc_cnt  = (int*)ws;                  // 640 ints
    int* counts  = (int*)(ws + 2560);         // 8 ints
    u64* gkeys   = (u64*)(ws + 2592);         // 8*80000 u64
    u64* pc_keys = (u64*)(ws + 5122592);      // 640*1000 u64

    hipMemsetAsync(ws, 0, 2592, stream);
    k_score<<<2000, 256, 0, stream>>>(logits, pc_cnt, pc_keys);
    k_nms<<<B_ * NC, 64, 0, stream>>>(pc_cnt, pc_keys, box_reg, props, gkeys, counts);
    k_topk<<<B_, 256, 0, stream>>>(counts, gkeys, box_reg, props, out);
    k_mask<<<(B_ * K_ * 196 + 255) / 256, 256, 0, stream>>>(mask_log, out);
}